// Round 4
// baseline (320.624 us; speedup 1.0000x reference)
//
#include <hip/hip_runtime.h>

// Problem constants (from reference)
#define N1C 50000
#define N2C 50000
#define NNC 16
#define NIC 64
#define NDC 128
#define QB  8     // queries per block
#define MR  128   // QB*NN rows per block
#define FELEMS (N1C * NIC)   // 3.2M elements per feature array

typedef __bf16 bf16x8 __attribute__((ext_vector_type(8)));
typedef float f32x4 __attribute__((ext_vector_type(4)));

#if defined(__has_builtin)
#if __has_builtin(__builtin_amdgcn_cvt_pk_bf16_f32)
#define HAVE_PK_BF16 1
#endif
#endif

#ifdef HAVE_PK_BF16
typedef __bf16 bf16x2 __attribute__((ext_vector_type(2)));
static __device__ __forceinline__ unsigned int pkbf(float a, float b) {
    bf16x2 r = __builtin_amdgcn_cvt_pk_bf16_f32(a, b);
    return __builtin_bit_cast(unsigned int, r);
}
#else
static __device__ __forceinline__ unsigned short f2bf_sw(float f) {
    unsigned int u = __builtin_bit_cast(unsigned int, f);
    u += 0x7fffu + ((u >> 16) & 1u);
    return (unsigned short)(u >> 16);
}
static __device__ __forceinline__ unsigned int pkbf(float a, float b) {
    return (unsigned int)f2bf_sw(a) | ((unsigned int)f2bf_sw(b) << 16);
}
#endif

static __device__ __forceinline__ float elu(float x) {
    return x > 0.f ? x : __expf(x) - 1.f;
}

// ---- prep 1: W^T bf16 images (stride 128): wsW[d*128+k] = bf16(W[k][d]) ----
__global__ void prep_w(const float* __restrict__ W1, const float* __restrict__ W2,
                       unsigned short* __restrict__ wsW) {
    const int idx = blockIdx.x * 256 + threadIdx.x;   // 0 .. 32767
    const int m   = idx >> 14;
    const int o   = idx & 16383;
    const int d   = o >> 7;
    const int k   = o & 127;
    const float* W = m ? W2 : W1;
    wsW[idx] = (unsigned short)pkbf(W[(size_t)k * NDC + d], 0.f);
}

// ---- prep 2: features1/features2 -> bf16 (8 floats per thread) ----
__global__ void prep_f(const float* __restrict__ f1, const float* __restrict__ f2,
                       unsigned short* __restrict__ dst) {   // dst = f1b (f2b follows)
    const int g = blockIdx.x * 256 + threadIdx.x;            // 0 .. 799999
    const size_t base = (size_t)g * 8;
    const float* src = (base < FELEMS) ? (f1 + base) : (f2 + base - FELEMS);
    const float4 v0 = *(const float4*)src;
    const float4 v1 = *(const float4*)(src + 4);
    uint4 o;
    o.x = pkbf(v0.x, v0.y);
    o.y = pkbf(v0.z, v0.w);
    o.z = pkbf(v1.x, v1.y);
    o.w = pkbf(v1.z, v1.w);
    *(uint4*)(dst + base) = o;
}

__global__ __launch_bounds__(256, 3)
void fused_knn_mlp(const unsigned short* __restrict__ f1b,
                   const unsigned short* __restrict__ f2b,
                   const float* __restrict__ x1,
                   const float* __restrict__ x2,
                   const int*   __restrict__ topk,
                   const float* __restrict__ b1,
                   const float* __restrict__ b2,
                   const float* __restrict__ radius,
                   const unsigned short* __restrict__ wsW,
                   float* __restrict__ out)
{
    // Single 32 KB tile: layer-1 A (128x128 bf16), then per-wave in-place h1.
    // XOR swizzle: 16B chunk c of row r stored at chunk (c ^ (r&15)).
    __shared__ unsigned short sX[MR * NDC];
    __shared__ float sWgt[MR];

    const int tid  = threadIdx.x;
    const int blk  = blockIdx.x;
    const int lane = tid & 63;
    const int wave = tid >> 6;
    const int quad = lane >> 4;
    const int l16  = lane & 15;

    // ---- stage A tile (gathers; bf16 source, pure copy) ----
    // f2 part: rows 0..127, cols 0..63 -> chunks 0..7
    #pragma unroll
    for (int j = 0; j < 4; ++j) {
        const int e = j * 256 + tid;    // 0..1023
        const int r = e >> 3;           // row
        const int c = e & 7;            // 16B chunk within f2 half
        const int idx = topk[blk * MR + r];
        const uint4 v = *(const uint4*)(f2b + (size_t)idx * NIC + c * 8);
        *(uint4*)&sX[r * NDC + (c ^ (r & 15)) * 8] = v;
    }
    // f1 part: cols 64..127 -> chunks 8..15, row's query = r>>4
    #pragma unroll
    for (int j = 0; j < 4; ++j) {
        const int e = j * 256 + tid;
        const int r = e >> 3;
        const int c = e & 7;
        const uint4 v = *(const uint4*)(f1b + (size_t)(blk * QB + (r >> 4)) * NIC + c * 8);
        *(uint4*)&sX[r * NDC + ((8 + c) ^ (r & 15)) * 8] = v;
    }

    // ---- per-wave distance weights for its own 32 rows ----
    if (lane < 32) {
        const int row = wave * 32 + lane;
        const int nq  = blk * QB + (row >> 4);
        const int idx = topk[blk * MR + row];
        const float rr = radius[0];
        const float inv2r2 = 1.f / (2.f * rr * rr);
        const float dx = x2[idx * 3 + 0] - x1[nq * 3 + 0];
        const float dy = x2[idx * 3 + 1] - x1[nq * 3 + 1];
        const float dz = x2[idx * 3 + 2] - x1[nq * 3 + 2];
        const float w = __expf(-(dx * dx + dy * dy + dz * dz) * inv2r2);
        sWgt[row] = (idx == 0) ? 0.f : w;
    }

    const unsigned short* wp1 = wsW;          // W1^T [d][k], stride 128
    const unsigned short* wp2 = wsW + 16384;  // W2^T

    // ---- prefetch layer-1 ks=0 B-frags (overlaps barrier drain) ----
    uint4 wb[2][8];
    #pragma unroll
    for (int nt = 0; nt < 8; ++nt)
        wb[0][nt] = *(const uint4*)(wp1 + (nt * 16 + l16) * NDC + quad * 8);

    f32x4 acc[2][8];
    #pragma unroll
    for (int nt = 0; nt < 8; ++nt) {
        acc[0][nt] = (f32x4){0.f, 0.f, 0.f, 0.f};
        acc[1][nt] = acc[0][nt];
    }

    __syncthreads();

    // ---- layer 1: acc = A @ W1 (double-buffered register B-frags) ----
    #pragma unroll
    for (int ks = 0; ks < 4; ++ks) {
        if (ks < 3) {
            #pragma unroll
            for (int nt = 0; nt < 8; ++nt)
                wb[(ks + 1) & 1][nt] =
                    *(const uint4*)(wp1 + (nt * 16 + l16) * NDC + (ks + 1) * 32 + quad * 8);
        }
        const int pc = ((ks * 4 + quad) ^ l16) * 8;
        const bf16x8 a0 = *(const bf16x8*)&sX[(wave * 32 + l16) * NDC + pc];
        const bf16x8 a1 = *(const bf16x8*)&sX[(wave * 32 + 16 + l16) * NDC + pc];
        #pragma unroll
        for (int nt = 0; nt < 8; ++nt) {
            const bf16x8 b = __builtin_bit_cast(bf16x8, wb[ks & 1][nt]);
            acc[0][nt] = __builtin_amdgcn_mfma_f32_16x16x32_bf16(a0, b, acc[0][nt], 0, 0, 0);
            acc[1][nt] = __builtin_amdgcn_mfma_f32_16x16x32_bf16(a1, b, acc[1][nt], 0, 0, 0);
        }
    }

    // ---- prefetch layer-2 ks=0 B-frags (overlaps h1 writeback VALU/LDS) ----
    #pragma unroll
    for (int nt = 0; nt < 8; ++nt)
        wb[0][nt] = *(const uint4*)(wp2 + (nt * 16 + l16) * NDC + quad * 8);

    // ---- h1 = elu(acc + b1) -> sX, in place over the wave's OWN 32 rows ----
    // C/D layout: col = nt*16 + l16, row(within tile) = quad*4 + reg  [m89/m91]
    #pragma unroll
    for (int mt = 0; mt < 2; ++mt) {
        const int q = wave * 2 + mt;
        #pragma unroll
        for (int nt = 0; nt < 8; ++nt) {
            const int col = nt * 16 + l16;
            const float bb = b1[col];
            const int chunk = nt * 2 + (l16 >> 3);
            const int o = l16 & 7;
            #pragma unroll
            for (int reg = 0; reg < 4; ++reg) {
                const int row = q * 16 + quad * 4 + reg;
                sX[row * NDC + (chunk ^ (row & 15)) * 8 + o] =
                    (unsigned short)pkbf(elu(acc[mt][nt][reg] + bb), 0.f);
            }
        }
    }

    // ---- layer 2: acc2 = h1 @ W2 (reads only own 32 rows; no barrier) ----
    f32x4 acc2[2][8];
    #pragma unroll
    for (int nt = 0; nt < 8; ++nt) {
        acc2[0][nt] = (f32x4){0.f, 0.f, 0.f, 0.f};
        acc2[1][nt] = acc2[0][nt];
    }
    #pragma unroll
    for (int ks = 0; ks < 4; ++ks) {
        if (ks < 3) {
            #pragma unroll
            for (int nt = 0; nt < 8; ++nt)
                wb[(ks + 1) & 1][nt] =
                    *(const uint4*)(wp2 + (nt * 16 + l16) * NDC + (ks + 1) * 32 + quad * 8);
        }
        const int pc = ((ks * 4 + quad) ^ l16) * 8;
        const bf16x8 a0 = *(const bf16x8*)&sX[(wave * 32 + l16) * NDC + pc];
        const bf16x8 a1 = *(const bf16x8*)&sX[(wave * 32 + 16 + l16) * NDC + pc];
        #pragma unroll
        for (int nt = 0; nt < 8; ++nt) {
            const bf16x8 b = __builtin_bit_cast(bf16x8, wb[ks & 1][nt]);
            acc2[0][nt] = __builtin_amdgcn_mfma_f32_16x16x32_bf16(a0, b, acc2[0][nt], 0, 0, 0);
            acc2[1][nt] = __builtin_amdgcn_mfma_f32_16x16x32_bf16(a1, b, acc2[1][nt], 0, 0, 0);
        }
    }

    // ---- epilogue: out[q][d] = sum_k w[k] * elu(h2[k][d] + b2[d]) ----
    #pragma unroll
    for (int mt = 0; mt < 2; ++mt) {
        const int q = wave * 2 + mt;
        const float4 wv = *(const float4*)&sWgt[q * 16 + quad * 4];
        #pragma unroll
        for (int nt = 0; nt < 8; ++nt) {
            const int col = nt * 16 + l16;
            const float bb = b2[col];
            float s = elu(acc2[mt][nt][0] + bb) * wv.x
                    + elu(acc2[mt][nt][1] + bb) * wv.y
                    + elu(acc2[mt][nt][2] + bb) * wv.z
                    + elu(acc2[mt][nt][3] + bb) * wv.w;
            s += __shfl_xor(s, 16, 64);
            s += __shfl_xor(s, 32, 64);
            if (lane < 16) {
                out[(size_t)(blk * QB + q) * NDC + col] = s;
            }
        }
    }
}

extern "C" void kernel_launch(void* const* d_in, const int* in_sizes, int n_in,
                              void* d_out, int out_size, void* d_ws, size_t ws_size,
                              hipStream_t stream) {
    const float* features1 = (const float*)d_in[0];
    const float* features2 = (const float*)d_in[1];
    const float* x1        = (const float*)d_in[2];
    const float* x2        = (const float*)d_in[3];
    // d_in[4], d_in[5] = nuv1, nuv2 (unused by reference)
    const int*   topk      = (const int*)d_in[6];
    const float* W1        = (const float*)d_in[7];
    const float* b1        = (const float*)d_in[8];
    const float* W2        = (const float*)d_in[9];
    const float* b2        = (const float*)d_in[10];
    const float* radius    = (const float*)d_in[11];
    float* out = (float*)d_out;

    unsigned short* wsW = (unsigned short*)d_ws;      // 32768 shorts = 64 KB
    unsigned short* f1b = wsW + 32768;                // 3.2M shorts
    unsigned short* f2b = f1b + FELEMS;               // 3.2M shorts

    prep_w<<<dim3(128), 256, 0, stream>>>(W1, W2, wsW);
    prep_f<<<dim3(3125), 256, 0, stream>>>(features1, features2, f1b);
    fused_knn_mlp<<<dim3(N1C / QB), 256, 0, stream>>>(f1b, f2b, x1, x2, topk,
                                                      b1, b2, radius, wsW, out);
}

// Round 5
// 259.722 us; speedup vs baseline: 1.2345x; 1.2345x over previous
//
#include <hip/hip_runtime.h>

// Problem constants (from reference)
#define N1C 50000
#define N2C 50000
#define NNC 16
#define NIC 64
#define NDC 128
#define QB  8     // queries per block
#define MR  128   // QB*NN rows per block
#define FELEMS (N1C * NIC)   // 3.2M elements per feature array

typedef __bf16 bf16x8 __attribute__((ext_vector_type(8)));
typedef float f32x4 __attribute__((ext_vector_type(4)));
typedef unsigned u32x4 __attribute__((ext_vector_type(4)));

#if defined(__has_builtin)
#if __has_builtin(__builtin_amdgcn_cvt_pk_bf16_f32)
#define HAVE_PK_BF16 1
#endif
#endif

#ifdef HAVE_PK_BF16
typedef __bf16 bf16x2 __attribute__((ext_vector_type(2)));
static __device__ __forceinline__ unsigned int pkbf(float a, float b) {
    bf16x2 r = __builtin_amdgcn_cvt_pk_bf16_f32(a, b);
    return __builtin_bit_cast(unsigned int, r);
}
#else
static __device__ __forceinline__ unsigned short f2bf_sw(float f) {
    unsigned int u = __builtin_bit_cast(unsigned int, f);
    u += 0x7fffu + ((u >> 16) & 1u);
    return (unsigned short)(u >> 16);
}
static __device__ __forceinline__ unsigned int pkbf(float a, float b) {
    return (unsigned int)f2bf_sw(a) | ((unsigned int)f2bf_sw(b) << 16);
}
#endif

static __device__ __forceinline__ float elu(float x) {
    return x > 0.f ? x : __expf(x) - 1.f;
}

// ---- prep 1: W^T bf16 images (row-major [d][k], stride 128): wsW[m*16384 + d*128 + k] = bf16(W[k][d]) ----
__global__ void prep_w(const float* __restrict__ W1, const float* __restrict__ W2,
                       unsigned short* __restrict__ wsW) {
    const int idx = blockIdx.x * 256 + threadIdx.x;   // 0 .. 32767
    const int m   = idx >> 14;
    const int o   = idx & 16383;
    const int d   = o >> 7;
    const int k   = o & 127;
    const float* W = m ? W2 : W1;
    wsW[idx] = (unsigned short)pkbf(W[(size_t)k * NDC + d], 0.f);
}

// ---- prep 2: features1/features2 -> bf16 (8 floats per thread) ----
__global__ void prep_f(const float* __restrict__ f1, const float* __restrict__ f2,
                       unsigned short* __restrict__ dst) {   // dst = f1b (f2b follows)
    const int g = blockIdx.x * 256 + threadIdx.x;            // 0 .. 799999
    const size_t base = (size_t)g * 8;
    const float* src = (base < FELEMS) ? (f1 + base) : (f2 + base - FELEMS);
    const float4 v0 = *(const float4*)src;
    const float4 v1 = *(const float4*)(src + 4);
    uint4 o;
    o.x = pkbf(v0.x, v0.y);
    o.y = pkbf(v0.z, v0.w);
    o.z = pkbf(v1.x, v1.y);
    o.w = pkbf(v1.z, v1.w);
    *(uint4*)(dst + base) = o;
}

// Swizzled LDS chunk address: logical 16B-chunk (row r, chunk c) -> phys index
static __device__ __forceinline__ int swz(int o /* r*16 + c */) {
    return (o & ~15) | ((o & 15) ^ ((o >> 4) & 15));
}

__global__ __launch_bounds__(256, 3)
void fused_knn_mlp(const unsigned short* __restrict__ f1b,
                   const unsigned short* __restrict__ f2b,
                   const float* __restrict__ x1,
                   const float* __restrict__ x2,
                   const int*   __restrict__ topk,
                   const float* __restrict__ b1,
                   const float* __restrict__ b2,
                   const float* __restrict__ radius,
                   const unsigned short* __restrict__ wsW,
                   float* __restrict__ out)
{
    __shared__ uint4 sW[2048];   // 32 KB: W1^T, then restaged as W2^T

    const int tid  = threadIdx.x;
    const int blk  = blockIdx.x;
    const int lane = tid & 63;
    const int wave = tid >> 6;
    const int quad = lane >> 4;
    const int l16  = lane & 15;

    // ---- this lane's two rows (one per row-tile) ----
    const int r0   = wave * 32 + l16;
    const int r1   = r0 + 16;
    const int idx0 = topk[blk * MR + r0];
    const int idx1 = topk[blk * MR + r1];
    const int q0   = blk * QB + wave * 2;
    const int q1   = q0 + 1;

    // ---- X B-frags: direct global gather (each row/chunk read exactly once) ----
    // k 0..63 = features2[idx] (neighbor), k 64..127 = features1[q] (self) — reference concat order.
    uint4 xf[2][4];
    #pragma unroll
    for (int ks = 0; ks < 2; ++ks) {
        xf[0][ks] = *(const uint4*)(f2b + (size_t)idx0 * NIC + ks * 32 + quad * 8);
        xf[1][ks] = *(const uint4*)(f2b + (size_t)idx1 * NIC + ks * 32 + quad * 8);
    }
    #pragma unroll
    for (int ks = 2; ks < 4; ++ks) {
        xf[0][ks] = *(const uint4*)(f1b + (size_t)q0 * NIC + (ks - 2) * 32 + quad * 8);
        xf[1][ks] = *(const uint4*)(f1b + (size_t)q1 * NIC + (ks - 2) * 32 + quad * 8);
    }

    // ---- stage W1^T into LDS (clean uint4 copy, XOR-swizzled) ----
    {
        const uint4* wp = (const uint4*)wsW;
        #pragma unroll
        for (int it = 0; it < 8; ++it) {
            const int o = it * 256 + tid;
            sW[swz(o)] = wp[o];
        }
    }

    // ---- distance weights for rows r0, r1 (all quads redundantly; used via shuffle later) ----
    float wg0, wg1;
    {
        const float rr = radius[0];
        const float inv2r2 = 1.f / (2.f * rr * rr);
        const float ax = x1[q0 * 3 + 0], ay = x1[q0 * 3 + 1], az = x1[q0 * 3 + 2];
        const float bx = x1[q1 * 3 + 0], by = x1[q1 * 3 + 1], bz = x1[q1 * 3 + 2];
        const float dx0 = x2[idx0 * 3 + 0] - ax, dy0 = x2[idx0 * 3 + 1] - ay, dz0 = x2[idx0 * 3 + 2] - az;
        const float dx1 = x2[idx1 * 3 + 0] - bx, dy1 = x2[idx1 * 3 + 1] - by, dz1 = x2[idx1 * 3 + 2] - bz;
        wg0 = (idx0 == 0) ? 0.f : __expf(-(dx0 * dx0 + dy0 * dy0 + dz0 * dz0) * inv2r2);
        wg1 = (idx1 == 0) ? 0.f : __expf(-(dx1 * dx1 + dy1 * dy1 + dz1 * dz1) * inv2r2);
    }

    __syncthreads();   // W1 visible

    // ---- layer 1 (swapped): D1[d1][r] = sum_k W1T[d1][k] * X[r][k] ----
    // A = W1T frag (lane l16 <-> d1 within mt tile), B = xf (lane l16 <-> row within nt tile)
    f32x4 acc[8][2];
    #pragma unroll
    for (int mt = 0; mt < 8; ++mt) {
        acc[mt][0] = (f32x4){0.f, 0.f, 0.f, 0.f};
        acc[mt][1] = acc[mt][0];
    }
    #pragma unroll
    for (int ks = 0; ks < 4; ++ks) {
        const bf16x8 x0 = __builtin_bit_cast(bf16x8, xf[0][ks]);
        const bf16x8 x1f = __builtin_bit_cast(bf16x8, xf[1][ks]);
        #pragma unroll
        for (int mt = 0; mt < 8; ++mt) {
            const int phys = (mt * 16 + l16) * 16 + ((ks * 4 + quad) ^ l16);
            const bf16x8 a = *(const bf16x8*)&sW[phys];
            acc[mt][0] = __builtin_amdgcn_mfma_f32_16x16x32_bf16(a, x0, acc[mt][0], 0, 0, 0);
            acc[mt][1] = __builtin_amdgcn_mfma_f32_16x16x32_bf16(a, x1f, acc[mt][1], 0, 0, 0);
        }
    }

    // ---- prefetch W2 image into short-lived regs (consumed right after barrier) ----
    uint4 w2r[8];
    {
        const uint4* wp2 = (const uint4*)(wsW + 16384);
        #pragma unroll
        for (int it = 0; it < 8; ++it)
            w2r[it] = wp2[it * 256 + tid];
    }

    // ---- elu + bias + pack h1^T pairs into P[mt][nt][r2] (register-only) ----
    // Lane (quad,l16) holds h1[r = wave*32+nt*16+l16][d = mt*16+quad*4+reg]
    unsigned P[8][2][2];
    #pragma unroll
    for (int mt = 0; mt < 8; ++mt) {
        const float4 b1v = *(const float4*)(b1 + mt * 16 + quad * 4);
        #pragma unroll
        for (int nt = 0; nt < 2; ++nt) {
            P[mt][nt][0] = pkbf(elu(acc[mt][nt][0] + b1v.x), elu(acc[mt][nt][1] + b1v.y));
            P[mt][nt][1] = pkbf(elu(acc[mt][nt][2] + b1v.z), elu(acc[mt][nt][3] + b1v.w));
        }
    }

    __syncthreads();   // all waves done reading W1
    #pragma unroll
    for (int it = 0; it < 8; ++it) {
        const int o = it * 256 + tid;
        sW[swz(o)] = w2r[it];
    }
    __syncthreads();   // W2 visible

    // ---- layer 2 (normal): D2[r][d2] = sum_d h1[r][d] * W2T[d2][d] ----
    // A-frags built from P via cross-quad shuffles; B = W2T from LDS.
    f32x4 acc2[2][8];
    #pragma unroll
    for (int nt2 = 0; nt2 < 8; ++nt2) {
        acc2[0][nt2] = (f32x4){0.f, 0.f, 0.f, 0.f};
        acc2[1][nt2] = acc2[0][nt2];
    }
    #pragma unroll
    for (int ks = 0; ks < 4; ++ks) {
        // A-frag for (ks, mt2): lane needs h1[r = wave*32+mt2*16+l16][d = ks*32+quad*8+j]
        // source: P[2ks + (quad>>1)][mt2][u&1] from lane ((2quad + (u>>1))&3)*16 + l16
        u32x4 a2[2];
        #pragma unroll
        for (int mt2 = 0; mt2 < 2; ++mt2) {
            #pragma unroll
            for (int u = 0; u < 4; ++u) {
                const int src = (((quad * 2) + (u >> 1)) & 3) * 16 + l16;
                const unsigned lo = __shfl(P[2 * ks][mt2][u & 1], src, 64);
                const unsigned hi = __shfl(P[2 * ks + 1][mt2][u & 1], src, 64);
                a2[mt2][u] = (quad & 2) ? hi : lo;
            }
        }
        const bf16x8 af0 = __builtin_bit_cast(bf16x8, a2[0]);
        const bf16x8 af1 = __builtin_bit_cast(bf16x8, a2[1]);
        #pragma unroll
        for (int nt2 = 0; nt2 < 8; ++nt2) {
            const int phys = (nt2 * 16 + l16) * 16 + ((ks * 4 + quad) ^ l16);
            const bf16x8 b = *(const bf16x8*)&sW[phys];
            acc2[0][nt2] = __builtin_amdgcn_mfma_f32_16x16x32_bf16(af0, b, acc2[0][nt2], 0, 0, 0);
            acc2[1][nt2] = __builtin_amdgcn_mfma_f32_16x16x32_bf16(af1, b, acc2[1][nt2], 0, 0, 0);
        }
    }

    // ---- epilogue: out[q][d2] = sum_rows w * elu(h2 + b2) ----
    // acc2 row = quad*4+reg (neighbor within query), col = l16 (d2 within nt2 tile)
    float wk0[4], wk1[4];
    #pragma unroll
    for (int reg = 0; reg < 4; ++reg) {
        const int src = (lane & 48) | (quad * 4 + reg);
        wk0[reg] = __shfl(wg0, src, 64);
        wk1[reg] = __shfl(wg1, src, 64);
    }
    #pragma unroll
    for (int mt2 = 0; mt2 < 2; ++mt2) {
        #pragma unroll
        for (int nt2 = 0; nt2 < 8; ++nt2) {
            const int d2 = nt2 * 16 + l16;
            const float bb = b2[d2];
            float s;
            if (mt2 == 0)
                s = elu(acc2[0][nt2][0] + bb) * wk0[0] + elu(acc2[0][nt2][1] + bb) * wk0[1]
                  + elu(acc2[0][nt2][2] + bb) * wk0[2] + elu(acc2[0][nt2][3] + bb) * wk0[3];
            else
                s = elu(acc2[1][nt2][0] + bb) * wk1[0] + elu(acc2[1][nt2][1] + bb) * wk1[1]
                  + elu(acc2[1][nt2][2] + bb) * wk1[2] + elu(acc2[1][nt2][3] + bb) * wk1[3];
            s += __shfl_xor(s, 16, 64);
            s += __shfl_xor(s, 32, 64);
            if (lane < 16) {
                out[(size_t)(blk * QB + wave * 2 + mt2) * NDC + d2] = s;
            }
        }
    }
}

extern "C" void kernel_launch(void* const* d_in, const int* in_sizes, int n_in,
                              void* d_out, int out_size, void* d_ws, size_t ws_size,
                              hipStream_t stream) {
    const float* features1 = (const float*)d_in[0];
    const float* features2 = (const float*)d_in[1];
    const float* x1        = (const float*)d_in[2];
    const float* x2        = (const float*)d_in[3];
    // d_in[4], d_in[5] = nuv1, nuv2 (unused by reference)
    const int*   topk      = (const int*)d_in[6];
    const float* W1        = (const float*)d_in[7];
    const float* b1        = (const float*)d_in[8];
    const float* W2        = (const float*)d_in[9];
    const float* b2        = (const float*)d_in[10];
    const float* radius    = (const float*)d_in[11];
    float* out = (float*)d_out;

    unsigned short* wsW = (unsigned short*)d_ws;      // 32768 shorts = 64 KB
    unsigned short* f1b = wsW + 32768;                // 3.2M shorts
    unsigned short* f2b = f1b + FELEMS;               // 3.2M shorts

    prep_w<<<dim3(128), 256, 0, stream>>>(W1, W2, wsW);
    prep_f<<<dim3(3125), 256, 0, stream>>>(features1, features2, f1b);
    fused_knn_mlp<<<dim3(N1C / QB), 256, 0, stream>>>(f1b, f2b, x1, x2, topk,
                                                      b1, b2, radius, wsW, out);
}